// Round 4
// baseline (668.643 us; speedup 1.0000x reference)
//
#include <hip/hip_runtime.h>

// 0.8*dice_loss(pred,target) + 0.2*soft_cldice_loss(pred,target)
// pred/target: (64,1,512,512) fp32 -> 1 fp32 scalar.
//
// soft_skeletonize = 10x: x = relu(x - (dil3(ero3(x)) - ero3(x)))
//   (inner relu dropped: dil3 includes self => dil3(e) >= e)
//   ero3 = 3x3 min-pool, x OOB -> +inf; dil3 = 3x3 max-pool, e OOB -> -inf
//
// R12: mega-kernel REPAIR. R11's temporal blocking was structurally right
// (traffic 1.44 GB -> 0.63 GB) but executed broken, per counters:
//   - VGPR=64 + WRITE_SIZE=321MB on a store-free kernel = launch_bounds(1024)
//     forced an 8-waves/EU register cap and spilled the y[CH] pipeline.
//     Fix: 512-thread blocks, __launch_bounds__(512,2). 160KB LDS means
//     1 block/CU anyway -> 2 waves/EU is the real occupancy -> 256-VGPR
//     budget; CH=10 pipeline (~200 VGPR) fits, no spill.
//   - SQ_LDS_BANK_CONFLICT=3.96e7: p[lane*2] float4 reads use 16/32 banks.
//     Fix: XOR swizzle of the float4 index within a row (j ^= (j>>3)&1),
//     applied on BOTH store and load sides -> all 32 banks, optimal 8cy/b128.
//   - Shrinking valid window [2k+2, TROWS-3-2k]: skip writeback outside it
//     (those rows are provably-never-read garbage) -> ~27% LDS-write cut.
// Race-freedom per iteration: read-all-into-registers, barrier, write,
// barrier. Image-OOB rows are +inf via gr-bounds in ldrow (independent of
// tile contents); e-rows OOB are -inf. Dice fused at load (raw data),
// pairing fused at end (skeleton data).
//
// Harness rules learned: d_ws too small -> state in __device__ BSS;
// never pass __device__ symbols as host-side kernel args; launch_bounds
// second arg must match REAL occupancy or the VGPR cap causes spills.

#define H 512
#define W 512
#define W4 (W / 4)
#define NIMG 64
#define IMG_ELEMS (H * W)
#define NDICE_SLOTS 64
#define ITERS 10

// float4-index swizzle within a 128-float4 row: spreads the lane*2 /
// lane*2+1 access pattern (stride 32B -> 16 banks) across all 32 banks.
#define SWZ(j) ((j) ^ (((j) >> 3) & 1))

__device__ float g_acc[NIMG * 4];                 // per-image pairing sums
__device__ float g_dice[NDICE_SLOTS * 16];        // spread dice accumulators

struct F8 { float4 a, b; };          // 8 consecutive columns per lane

__device__ __forceinline__ F8 f8fill(float v) {
  F8 r; r.a = make_float4(v, v, v, v); r.b = r.a; return r;
}
__device__ __forceinline__ F8 f8min(const F8& x, const F8& y) {
  F8 r;
  r.a.x = fminf(x.a.x, y.a.x); r.a.y = fminf(x.a.y, y.a.y);
  r.a.z = fminf(x.a.z, y.a.z); r.a.w = fminf(x.a.w, y.a.w);
  r.b.x = fminf(x.b.x, y.b.x); r.b.y = fminf(x.b.y, y.b.y);
  r.b.z = fminf(x.b.z, y.b.z); r.b.w = fminf(x.b.w, y.b.w);
  return r;
}
__device__ __forceinline__ F8 f8max(const F8& x, const F8& y) {
  F8 r;
  r.a.x = fmaxf(x.a.x, y.a.x); r.a.y = fmaxf(x.a.y, y.a.y);
  r.a.z = fmaxf(x.a.z, y.a.z); r.a.w = fmaxf(x.a.w, y.a.w);
  r.b.x = fmaxf(x.b.x, y.b.x); r.b.y = fmaxf(x.b.y, y.b.y);
  r.b.z = fmaxf(x.b.z, y.b.z); r.b.w = fmaxf(x.b.w, y.b.w);
  return r;
}
// horizontal 3-tap min; L/R image edges see +inf
__device__ __forceinline__ F8 ero8(const F8& v, int lane) {
  float L = __shfl_up(v.b.w, 1, 64);
  if (lane == 0) L = __builtin_inff();
  float R = __shfl_down(v.a.x, 1, 64);
  if (lane == 63) R = __builtin_inff();
  F8 e;
  e.a.x = fminf(L,     fminf(v.a.x, v.a.y));
  e.a.y = fminf(v.a.x, fminf(v.a.y, v.a.z));
  e.a.z = fminf(v.a.y, fminf(v.a.z, v.a.w));
  e.a.w = fminf(v.a.z, fminf(v.a.w, v.b.x));
  e.b.x = fminf(v.a.w, fminf(v.b.x, v.b.y));
  e.b.y = fminf(v.b.x, fminf(v.b.y, v.b.z));
  e.b.z = fminf(v.b.y, fminf(v.b.z, v.b.w));
  e.b.w = fminf(v.b.z, fminf(v.b.w, R));
  return e;
}
// horizontal 3-tap max; edges see -inf
__device__ __forceinline__ F8 dil8(const F8& v, int lane) {
  float L = __shfl_up(v.b.w, 1, 64);
  if (lane == 0) L = -__builtin_inff();
  float R = __shfl_down(v.a.x, 1, 64);
  if (lane == 63) R = -__builtin_inff();
  F8 d;
  d.a.x = fmaxf(L,     fmaxf(v.a.x, v.a.y));
  d.a.y = fmaxf(v.a.x, fmaxf(v.a.y, v.a.z));
  d.a.z = fmaxf(v.a.y, fmaxf(v.a.z, v.a.w));
  d.a.w = fmaxf(v.a.z, fmaxf(v.a.w, v.b.x));
  d.b.x = fmaxf(v.a.w, fmaxf(v.b.x, v.b.y));
  d.b.y = fmaxf(v.b.x, fmaxf(v.b.y, v.b.z));
  d.b.z = fmaxf(v.b.y, fmaxf(v.b.z, v.b.w));
  d.b.w = fmaxf(v.b.z, fmaxf(v.b.w, R));
  return d;
}
__device__ __forceinline__ F8 f8sub(const F8& x, const F8& y) {
  F8 r;
  r.a.x = x.a.x - y.a.x; r.a.y = x.a.y - y.a.y;
  r.a.z = x.a.z - y.a.z; r.a.w = x.a.w - y.a.w;
  r.b.x = x.b.x - y.b.x; r.b.y = x.b.y - y.b.y;
  r.b.z = x.b.z - y.b.z; r.b.w = x.b.w - y.b.w;
  return r;
}
__device__ __forceinline__ F8 f8relu_sub(const F8& x, const F8& y) {
  F8 r;
  r.a.x = fmaxf(x.a.x - y.a.x, 0.f); r.a.y = fmaxf(x.a.y - y.a.y, 0.f);
  r.a.z = fmaxf(x.a.z - y.a.z, 0.f); r.a.w = fmaxf(x.a.w - y.a.w, 0.f);
  r.b.x = fmaxf(x.b.x - y.b.x, 0.f); r.b.y = fmaxf(x.b.y - y.b.y, 0.f);
  r.b.z = fmaxf(x.b.z - y.b.z, 0.f); r.b.w = fmaxf(x.b.w - y.b.w, 0.f);
  return r;
}

// TROWS rows in 160KB LDS; RR = TROWS - 40 owned rows (halo 20/side for 10
// iters at 2 rows/iter/side). Block = 512 threads = 8 waves; wave owns
// CH = TROWS/8 rows. One block/CU (LDS-bound) -> 2 waves/EU occupancy.
template <int TROWS, int RR>
__global__ __launch_bounds__(512, 2) void mega(
    const float* __restrict__ pred, const float* __restrict__ target) {
  extern __shared__ float tile[];                  // TROWS * W floats
  constexpr int NSTRIP = (H + RR - 1) / RR;
  constexpr int HALO = (TROWS - RR) / 2;           // 20
  constexpr int CH = TROWS / 8;                    // rows per wave
  const float PINF = __builtin_inff();

  const int u     = blockIdx.x / NSTRIP;           // 0..127 (chain element)
  const int strip = blockIdx.x % NSTRIP;
  const int g0    = strip * RR;
  const int nown  = min(H - g0, RR);               // owned rows (ragged tail)
  const bool isPred = (u < NIMG);
  const int img  = isPred ? u : u - NIMG;
  const float* src   = (isPred ? pred : target) + (size_t)img * IMG_ELEMS;
  const float* other = (isPred ? target : pred) + (size_t)img * IMG_ELEMS;

  const int tid  = threadIdx.x;
  const int lane = tid & 63;
  const int wave = tid >> 6;                       // 0..7
  const int gbase = g0 - HALO;                     // global row of tile row 0
  const int offA = SWZ(2 * lane);                  // swizzled float4 slots
  const int offB = SWZ(2 * lane + 1);

  float4* t4 = (float4*)tile;

  // ---- load tile (image rows [gbase, gbase+TROWS) ∩ [0,H)), swizzled ----
  {
    const float4* s4 = (const float4*)src;
    for (int i = tid; i < TROWS * W4; i += 512) {
      int r = i >> 7, j = i & 127;                 // W4 == 128
      int gr = gbase + r;
      if (gr >= 0 && gr < H) t4[(r << 7) + SWZ(j)] = s4[(size_t)gr * W4 + j];
    }
  }
  __syncthreads();

  // ---- dice sums on raw data (owned rows only) ----
  {
    float a0 = 0.f, a1 = 0.f;
    const float4* o4 = (const float4*)(other + (size_t)g0 * W);
    for (int i = tid; i < nown * W4; i += 512) {
      int r = i >> 7, j = i & 127;
      float4 x = t4[((HALO + r) << 7) + SWZ(j)];
      if (isPred) {
        float4 t = o4[i];
        a0 += x.x * t.x + x.y * t.y + x.z * t.z + x.w * t.w;
        a1 += x.x + x.y + x.z + x.w;
      } else {
        a0 += x.x + x.y + x.z + x.w;               // target-sum role
      }
    }
    #pragma unroll
    for (int o = 32; o; o >>= 1) {
      a0 += __shfl_down(a0, o, 64);
      a1 += __shfl_down(a1, o, 64);
    }
    if (lane == 0) {
      float* slot = &g_dice[(blockIdx.x & (NDICE_SLOTS - 1)) * 16];
      if (isPred) { atomicAdd(slot + 0, a0); atomicAdd(slot + 1, a1); }
      else        { atomicAdd(slot + 2, a0); }
    }
  }

  // ---- 10 in-LDS skeletonize iterations ----
  const int tb = wave * CH;                        // first tile row of chunk
  auto ldrow = [&](int tr) -> F8 {
    int gr = gbase + tr;
    F8 v;
    if (gr >= 0 && gr < H) {
      int trc = tr < 0 ? 0 : (tr >= TROWS ? TROWS - 1 : tr);
      const float4* p = t4 + ((size_t)trc << 7);
      v.a = p[offA]; v.b = p[offB];
    } else {
      v = f8fill(PINF);                            // true image OOB: +inf
    }
    return v;
  };
  auto erow = [&](const F8& x0, const F8& x1, const F8& x2, int tr) -> F8 {
    F8 e = ero8(f8min(f8min(x0, x1), x2), lane);
    int gr = gbase + tr;
    if (gr < 0 || gr >= H) e = f8fill(-PINF);      // e OOB: -inf (dil pad)
    return e;
  };

  for (int k = 0; k < ITERS; ++k) {
    __syncthreads();                               // prior writes visible
    // valid-output window after this iteration (rows outside are garbage
    // that is provably never read downstream)
    const int lo = 2 * k + 2;
    const int hi = TROWS - 3 - 2 * k;

    // read-only compute of CH rows into registers (static indexing only)
    F8 xm = ldrow(tb - 2);
    F8 xc = ldrow(tb - 1);
    F8 xp = ldrow(tb);
    F8 eM = erow(xm, xc, xp, tb - 1);              // e[tb-1]
    F8 xq = ldrow(tb + 1);
    F8 eC = erow(xc, xp, xq, tb);                  // e[tb]
    F8 y[CH];
    #pragma unroll
    for (int i = 0; i < CH; ++i) {
      F8 xn = ldrow(tb + 2 + i);
      F8 eP = erow(xp, xq, xn, tb + 1 + i);        // e[tb+1+i]
      F8 d  = dil8(f8max(f8max(eM, eC), eP), lane);
      y[i]  = f8relu_sub(xp, f8sub(d, eC));        // relu(x - (dil - ero))
      xp = xq; xq = xn; eM = eC; eC = eP;
    }
    __syncthreads();                               // all reads done
    #pragma unroll
    for (int i = 0; i < CH; ++i) {
      int row = tb + i;
      if (row >= lo && row <= hi) {                // skip never-read garbage
        float4* p = t4 + ((size_t)row << 7);
        p[offA] = y[i].a;
        p[offB] = y[i].b;
      }
    }
  }
  __syncthreads();

  // ---- pairing sums on skeleton (owned rows) ----
  {
    float b0 = 0.f, b1 = 0.f;
    const float4* o4 = (const float4*)(other + (size_t)g0 * W);
    for (int i = tid; i < nown * W4; i += 512) {
      int r = i >> 7, j = i & 127;
      float4 x = t4[((HALO + r) << 7) + SWZ(j)];
      float4 t = o4[i];
      b0 += x.x * t.x + x.y * t.y + x.z * t.z + x.w * t.w;
      b1 += x.x + x.y + x.z + x.w;
    }
    #pragma unroll
    for (int o = 32; o; o >>= 1) {
      b0 += __shfl_down(b0, o, 64);
      b1 += __shfl_down(b1, o, 64);
    }
    if (lane == 0) {
      const int base = img * 4 + (isPred ? 0 : 2);
      atomicAdd(&g_acc[base + 0], b0);             // sum(skel * other)
      atomicAdd(&g_acc[base + 1], b1);             // sum(skel)
    }
  }
}

__global__ void zero_acc() {
  for (int i = threadIdx.x; i < NIMG * 4; i += 256) g_acc[i] = 0.0f;
  for (int i = threadIdx.x; i < NDICE_SLOTS * 16; i += 256) g_dice[i] = 0.0f;
}

__global__ void final_kernel(float* __restrict__ out) {
  const int lane = threadIdx.x;  // 64 threads = 64 images / 64 dice slots
  float s1 = g_acc[lane * 4 + 0], s2 = g_acc[lane * 4 + 1];
  float s3 = g_acc[lane * 4 + 2], s4 = g_acc[lane * 4 + 3];
  float iflat = (s1 + 1.0f) / (s2 + 1.0f);
  float tflat = (s3 + 1.0f) / (s4 + 1.0f);
  float prod = iflat * tflat;
  float ssum = iflat + tflat;
  float d0 = g_dice[lane * 16 + 0];
  float d1 = g_dice[lane * 16 + 1];
  float d2 = g_dice[lane * 16 + 2];
  #pragma unroll
  for (int o = 32; o; o >>= 1) {
    prod += __shfl_down(prod, o, 64);
    ssum += __shfl_down(ssum, o, 64);
    d0   += __shfl_down(d0, o, 64);
    d1   += __shfl_down(d1, o, 64);
    d2   += __shfl_down(d2, o, 64);
  }
  if (lane == 0) {
    float cldice = 1.0f - 2.0f * prod / ssum;
    float dice = 1.0f - (2.0f * d0 + 1e-6f) / (d1 + d2 + 1e-6f);
    out[0] = 0.8f * dice + 0.2f * cldice;
  }
}

extern "C" void kernel_launch(void* const* d_in, const int* in_sizes, int n_in,
                              void* d_out, int out_size, void* d_ws, size_t ws_size,
                              hipStream_t stream) {
  const float* pred   = (const float*)d_in[0];
  const float* target = (const float*)d_in[1];
  float* out = (float*)d_out;
  (void)d_ws; (void)ws_size;

  // 160 KB LDS variant (80-row tile, RR=40) with 128 KB fallback (64-row).
  static int use80 = -1;
  if (use80 < 0) {
    hipError_t e = hipFuncSetAttribute(
        reinterpret_cast<const void*>(mega<80, 40>),
        hipFuncAttributeMaxDynamicSharedMemorySize, 80 * W * 4);
    use80 = (e == hipSuccess) ? 1 : 0;
    if (!use80) {
      (void)hipFuncSetAttribute(
          reinterpret_cast<const void*>(mega<64, 24>),
          hipFuncAttributeMaxDynamicSharedMemorySize, 64 * W * 4);
    }
  }

  zero_acc<<<1, 256, 0, stream>>>();
  if (use80) {
    constexpr int NSTRIP = (H + 39) / 40;          // 13
    mega<80, 40><<<128 * NSTRIP, 512, 80 * W * 4, stream>>>(pred, target);
  } else {
    constexpr int NSTRIP = (H + 23) / 24;          // 22
    mega<64, 24><<<128 * NSTRIP, 512, 64 * W * 4, stream>>>(pred, target);
  }
  final_kernel<<<1, 64, 0, stream>>>(out);
}

// Round 6
// 604.607 us; speedup vs baseline: 1.1059x; 1.1059x over previous
//
#include <hip/hip_runtime.h>

// 0.8*dice_loss(pred,target) + 0.2*soft_cldice_loss(pred,target)
// pred/target: (64,1,512,512) fp32 -> 1 fp32 scalar.
//
// soft_skeletonize = 10x: x = relu(x - (dil3(ero3(x)) - ero3(x)))
//   (inner relu dropped: dil3 includes self => dil3(e) >= e)
//   ero3 = 3x3 min-pool, x OOB -> +inf; dil3 = 3x3 max-pool, e OOB -> -inf
//
// R14 = R13 resubmission: R13's bench died with an infra-side "container
// failed twice" (no compile error, no pass/fail verdict, no counters).
// Kernel re-audited: uniform barriers, bounded LDS indices, race-free
// in-place scheme (reads lead writes by 3 rows; cross-wave rows register-
// cached in Phase A). Launch pattern (160KB dynamic LDS + 1024 threads +
// hipFuncSetAttribute) is identical to R11/R12 which ran fine.
//
// R13: SPILL-FREE mega-kernel. R12 counters: VGPR=128 + WRITE_SIZE=91MB on
// an atomics-only kernel = the y[CH] write-back buffer spilled to scratch;
// Occupancy 22% (8 waves/CU) couldn't hide scratch latency -> 577us.
// Fix: eliminate y[] entirely via a halo-register scheme:
//   per iteration: barrier; Phase A: cache the 4 cross-wave rows
//   (rs-2, rs-1, re+1, re+2) in registers (read-only, all waves); barrier;
//   Phase B: rolling pipeline over rows rs..re writing IN-PLACE to LDS.
//   Self-safe: reads lead writes by 3 rows. Neighbor-safe: all rows that
//   other waves write this iteration were register-cached in Phase A.
// This drops register demand to ~110 -> fits 128-VGPR cap, so we return to
// 1024 threads (16 waves/CU, CH=5) with __launch_bounds__(1024,4).
// Also: skip computing rows outside the shrinking valid window
// [2k+2, TROWS-3-2k] (garbage-by-construction, ~25% VALU saved), and
// prefetch the pipeline's LDS row 1 row ahead.
//
// Harness rules learned: d_ws too small -> state in __device__ BSS;
// never pass __device__ symbols as host-side kernel args; launch_bounds
// must leave headroom for the real register demand or scratch spill
// (phantom WRITE_SIZE) eats the kernel.

#define H 512
#define W 512
#define W4 (W / 4)
#define NIMG 64
#define IMG_ELEMS (H * W)
#define NDICE_SLOTS 64
#define ITERS 10

// float4-index swizzle within a 128-float4 row: spreads the lane*2 /
// lane*2+1 access pattern (stride 32B -> 16 banks) across all 32 banks.
#define SWZ(j) ((j) ^ (((j) >> 3) & 1))

__device__ float g_acc[NIMG * 4];                 // per-image pairing sums
__device__ float g_dice[NDICE_SLOTS * 16];        // spread dice accumulators

struct F8 { float4 a, b; };          // 8 consecutive columns per lane

__device__ __forceinline__ F8 f8fill(float v) {
  F8 r; r.a = make_float4(v, v, v, v); r.b = r.a; return r;
}
__device__ __forceinline__ F8 f8min(const F8& x, const F8& y) {
  F8 r;
  r.a.x = fminf(x.a.x, y.a.x); r.a.y = fminf(x.a.y, y.a.y);
  r.a.z = fminf(x.a.z, y.a.z); r.a.w = fminf(x.a.w, y.a.w);
  r.b.x = fminf(x.b.x, y.b.x); r.b.y = fminf(x.b.y, y.b.y);
  r.b.z = fminf(x.b.z, y.b.z); r.b.w = fminf(x.b.w, y.b.w);
  return r;
}
__device__ __forceinline__ F8 f8max(const F8& x, const F8& y) {
  F8 r;
  r.a.x = fmaxf(x.a.x, y.a.x); r.a.y = fmaxf(x.a.y, y.a.y);
  r.a.z = fmaxf(x.a.z, y.a.z); r.a.w = fmaxf(x.a.w, y.a.w);
  r.b.x = fmaxf(x.b.x, y.b.x); r.b.y = fmaxf(x.b.y, y.b.y);
  r.b.z = fmaxf(x.b.z, y.b.z); r.b.w = fmaxf(x.b.w, y.b.w);
  return r;
}
// horizontal 3-tap min; L/R image edges see +inf
__device__ __forceinline__ F8 ero8(const F8& v, int lane) {
  float L = __shfl_up(v.b.w, 1, 64);
  if (lane == 0) L = __builtin_inff();
  float R = __shfl_down(v.a.x, 1, 64);
  if (lane == 63) R = __builtin_inff();
  F8 e;
  e.a.x = fminf(L,     fminf(v.a.x, v.a.y));
  e.a.y = fminf(v.a.x, fminf(v.a.y, v.a.z));
  e.a.z = fminf(v.a.y, fminf(v.a.z, v.a.w));
  e.a.w = fminf(v.a.z, fminf(v.a.w, v.b.x));
  e.b.x = fminf(v.a.w, fminf(v.b.x, v.b.y));
  e.b.y = fminf(v.b.x, fminf(v.b.y, v.b.z));
  e.b.z = fminf(v.b.y, fminf(v.b.z, v.b.w));
  e.b.w = fminf(v.b.z, fminf(v.b.w, R));
  return e;
}
// horizontal 3-tap max; edges see -inf
__device__ __forceinline__ F8 dil8(const F8& v, int lane) {
  float L = __shfl_up(v.b.w, 1, 64);
  if (lane == 0) L = -__builtin_inff();
  float R = __shfl_down(v.a.x, 1, 64);
  if (lane == 63) R = -__builtin_inff();
  F8 d;
  d.a.x = fmaxf(L,     fmaxf(v.a.x, v.a.y));
  d.a.y = fmaxf(v.a.x, fmaxf(v.a.y, v.a.z));
  d.a.z = fmaxf(v.a.y, fmaxf(v.a.z, v.a.w));
  d.a.w = fmaxf(v.a.z, fmaxf(v.a.w, v.b.x));
  d.b.x = fmaxf(v.a.w, fmaxf(v.b.x, v.b.y));
  d.b.y = fmaxf(v.b.x, fmaxf(v.b.y, v.b.z));
  d.b.z = fmaxf(v.b.y, fmaxf(v.b.z, v.b.w));
  d.b.w = fmaxf(v.b.z, fmaxf(v.b.w, R));
  return d;
}
__device__ __forceinline__ F8 f8sub(const F8& x, const F8& y) {
  F8 r;
  r.a.x = x.a.x - y.a.x; r.a.y = x.a.y - y.a.y;
  r.a.z = x.a.z - y.a.z; r.a.w = x.a.w - y.a.w;
  r.b.x = x.b.x - y.b.x; r.b.y = x.b.y - y.b.y;
  r.b.z = x.b.z - y.b.z; r.b.w = x.b.w - y.b.w;
  return r;
}
__device__ __forceinline__ F8 f8relu_sub(const F8& x, const F8& y) {
  F8 r;
  r.a.x = fmaxf(x.a.x - y.a.x, 0.f); r.a.y = fmaxf(x.a.y - y.a.y, 0.f);
  r.a.z = fmaxf(x.a.z - y.a.z, 0.f); r.a.w = fmaxf(x.a.w - y.a.w, 0.f);
  r.b.x = fmaxf(x.b.x - y.b.x, 0.f); r.b.y = fmaxf(x.b.y - y.b.y, 0.f);
  r.b.z = fmaxf(x.b.z - y.b.z, 0.f); r.b.w = fmaxf(x.b.w - y.b.w, 0.f);
  return r;
}

// TROWS rows in 160KB LDS; RR = TROWS - 40 owned rows (halo 20/side).
// Block = 1024 threads = 16 waves; wave owns CH = TROWS/16 rows.
// 160KB LDS -> 1 block/CU -> 16 waves/CU = 4 waves/EU -> 128-VGPR cap.
template <int TROWS, int RR>
__global__ __launch_bounds__(1024, 4) void mega(
    const float* __restrict__ pred, const float* __restrict__ target) {
  extern __shared__ float tile[];                  // TROWS * W floats
  constexpr int NSTRIP = (H + RR - 1) / RR;
  constexpr int HALO = (TROWS - RR) / 2;           // 20
  constexpr int CH = TROWS / 16;                   // rows per wave (5)
  const float PINF = __builtin_inff();

  const int u     = blockIdx.x / NSTRIP;           // 0..127 (chain element)
  const int strip = blockIdx.x % NSTRIP;
  const int g0    = strip * RR;
  const int nown  = min(H - g0, RR);               // owned rows (ragged tail)
  const bool isPred = (u < NIMG);
  const int img  = isPred ? u : u - NIMG;
  const float* src   = (isPred ? pred : target) + (size_t)img * IMG_ELEMS;
  const float* other = (isPred ? target : pred) + (size_t)img * IMG_ELEMS;

  const int tid  = threadIdx.x;
  const int lane = tid & 63;
  const int wave = tid >> 6;                       // 0..15
  const int gbase = g0 - HALO;                     // global row of tile row 0
  const int offA = SWZ(2 * lane);                  // swizzled float4 slots
  const int offB = SWZ(2 * lane + 1);

  float4* t4 = (float4*)tile;

  // ---- load tile (image rows [gbase, gbase+TROWS) ∩ [0,H)), swizzled ----
  {
    const float4* s4 = (const float4*)src;
    for (int i = tid; i < TROWS * W4; i += 1024) {
      int r = i >> 7, j = i & 127;                 // W4 == 128
      int gr = gbase + r;
      if (gr >= 0 && gr < H) t4[(r << 7) + SWZ(j)] = s4[(size_t)gr * W4 + j];
    }
  }
  __syncthreads();

  // ---- dice sums on raw data (owned rows only) ----
  {
    float a0 = 0.f, a1 = 0.f;
    const float4* o4 = (const float4*)(other + (size_t)g0 * W);
    for (int i = tid; i < nown * W4; i += 1024) {
      int r = i >> 7, j = i & 127;
      float4 x = t4[((HALO + r) << 7) + SWZ(j)];
      if (isPred) {
        float4 t = o4[i];
        a0 += x.x * t.x + x.y * t.y + x.z * t.z + x.w * t.w;
        a1 += x.x + x.y + x.z + x.w;
      } else {
        a0 += x.x + x.y + x.z + x.w;               // target-sum role
      }
    }
    #pragma unroll
    for (int o = 32; o; o >>= 1) {
      a0 += __shfl_down(a0, o, 64);
      a1 += __shfl_down(a1, o, 64);
    }
    if (lane == 0) {
      float* slot = &g_dice[(blockIdx.x & (NDICE_SLOTS - 1)) * 16];
      if (isPred) { atomicAdd(slot + 0, a0); atomicAdd(slot + 1, a1); }
      else        { atomicAdd(slot + 2, a0); }
    }
  }

  // ---- 10 in-LDS skeletonize iterations, in-place with halo registers ----
  const int tb = wave * CH;
  auto ldrow = [&](int tr) -> F8 {
    int gr = gbase + tr;
    F8 v;
    if (gr >= 0 && gr < H) {
      const float4* p = t4 + ((size_t)tr << 7);
      v.a = p[offA]; v.b = p[offB];
    } else {
      v = f8fill(PINF);                            // true image OOB: +inf
    }
    return v;
  };
  auto erow = [&](const F8& x0, const F8& x1, const F8& x2, int tr) -> F8 {
    F8 e = ero8(f8min(f8min(x0, x1), x2), lane);
    int gr = gbase + tr;
    if (gr < 0 || gr >= H) e = f8fill(-PINF);      // e OOB: -inf (dil pad)
    return e;
  };

  for (int k = 0; k < ITERS; ++k) {
    // valid-output window this iteration; rows outside are never read again
    const int lo = 2 * k + 2;
    const int hi = TROWS - 3 - 2 * k;
    const int rs = max(tb, lo);
    const int re = min(tb + CH - 1, hi);
    const bool active = (rs <= re);

    __syncthreads();                               // iter k-1 writes visible

    // Phase A: register-cache every row that another wave may overwrite
    // (and our upper inputs) BEFORE anyone writes. Read-only, all waves.
    F8 A2 = f8fill(0.f), A1 = A2, B1 = A2, B2 = A2;
    if (active) {
      A2 = ldrow(rs - 2);                          // rows rs-2..re+2 are all
      A1 = ldrow(rs - 1);                          // in V_{k-1}: rs-2>=2k>=0,
      B1 = ldrow(re + 1);                          // re+2<=TROWS-1-2k
      B2 = ldrow(re + 2);
    }
    __syncthreads();                               // Phase A done

    // Phase B: rolling pipeline rows rs..re, writing in-place.
    if (active) {
      auto rdx = [&](int r) -> F8 {                // substitute cached halos
        if (r == re + 1) return B1;
        if (r == re + 2) return B2;
        return ldrow(r);                           // own rows only (LDS)
      };
      // warmup: x[rs..rs+2], e[rs-1..rs+1]
      F8 xc = rdx(rs);                             // x[r]
      F8 xd = rdx(rs + 1);                         // x[r+1]
      F8 xe = rdx(rs + 2);                         // x[r+2]
      F8 eM = erow(A2, A1, xc, rs - 1);
      F8 eC = erow(A1, xc, xd, rs);
      F8 eP = erow(xc, xd, xe, rs + 1);
      #pragma unroll 1
      for (int r = rs; r <= re; ++r) {
        // prefetch next x row early (use at eN, ~60 ops later)
        F8 xf = (r < re) ? rdx(r + 3) : xe;        // guard: no read past re+2
        F8 d = dil8(f8max(f8max(eM, eC), eP), lane);
        F8 y = f8relu_sub(xc, f8sub(d, eC));       // relu(x - (dil - ero))
        float4* p = t4 + ((size_t)r << 7);         // in-place: reads lead
        p[offA] = y.a;                             // writes by 3 rows
        p[offB] = y.b;
        F8 eN = erow(xd, xe, xf, r + 2);
        xc = xd; xd = xe; xe = xf;
        eM = eC; eC = eP; eP = eN;
      }
    }
  }
  __syncthreads();

  // ---- pairing sums on skeleton (owned rows) ----
  {
    float b0 = 0.f, b1 = 0.f;
    const float4* o4 = (const float4*)(other + (size_t)g0 * W);
    for (int i = tid; i < nown * W4; i += 1024) {
      int r = i >> 7, j = i & 127;
      float4 x = t4[((HALO + r) << 7) + SWZ(j)];
      float4 t = o4[i];
      b0 += x.x * t.x + x.y * t.y + x.z * t.z + x.w * t.w;
      b1 += x.x + x.y + x.z + x.w;
    }
    #pragma unroll
    for (int o = 32; o; o >>= 1) {
      b0 += __shfl_down(b0, o, 64);
      b1 += __shfl_down(b1, o, 64);
    }
    if (lane == 0) {
      const int base = img * 4 + (isPred ? 0 : 2);
      atomicAdd(&g_acc[base + 0], b0);             // sum(skel * other)
      atomicAdd(&g_acc[base + 1], b1);             // sum(skel)
    }
  }
}

__global__ void zero_acc() {
  for (int i = threadIdx.x; i < NIMG * 4; i += 256) g_acc[i] = 0.0f;
  for (int i = threadIdx.x; i < NDICE_SLOTS * 16; i += 256) g_dice[i] = 0.0f;
}

__global__ void final_kernel(float* __restrict__ out) {
  const int lane = threadIdx.x;  // 64 threads = 64 images / 64 dice slots
  float s1 = g_acc[lane * 4 + 0], s2 = g_acc[lane * 4 + 1];
  float s3 = g_acc[lane * 4 + 2], s4 = g_acc[lane * 4 + 3];
  float iflat = (s1 + 1.0f) / (s2 + 1.0f);
  float tflat = (s3 + 1.0f) / (s4 + 1.0f);
  float prod = iflat * tflat;
  float ssum = iflat + tflat;
  float d0 = g_dice[lane * 16 + 0];
  float d1 = g_dice[lane * 16 + 1];
  float d2 = g_dice[lane * 16 + 2];
  #pragma unroll
  for (int o = 32; o; o >>= 1) {
    prod += __shfl_down(prod, o, 64);
    ssum += __shfl_down(ssum, o, 64);
    d0   += __shfl_down(d0, o, 64);
    d1   += __shfl_down(d1, o, 64);
    d2   += __shfl_down(d2, o, 64);
  }
  if (lane == 0) {
    float cldice = 1.0f - 2.0f * prod / ssum;
    float dice = 1.0f - (2.0f * d0 + 1e-6f) / (d1 + d2 + 1e-6f);
    out[0] = 0.8f * dice + 0.2f * cldice;
  }
}

extern "C" void kernel_launch(void* const* d_in, const int* in_sizes, int n_in,
                              void* d_out, int out_size, void* d_ws, size_t ws_size,
                              hipStream_t stream) {
  const float* pred   = (const float*)d_in[0];
  const float* target = (const float*)d_in[1];
  float* out = (float*)d_out;
  (void)d_ws; (void)ws_size;

  // 160 KB LDS variant (80-row tile, RR=40) with 128 KB fallback (64-row).
  static int use80 = -1;
  if (use80 < 0) {
    hipError_t e = hipFuncSetAttribute(
        reinterpret_cast<const void*>(mega<80, 40>),
        hipFuncAttributeMaxDynamicSharedMemorySize, 80 * W * 4);
    use80 = (e == hipSuccess) ? 1 : 0;
    if (!use80) {
      (void)hipFuncSetAttribute(
          reinterpret_cast<const void*>(mega<64, 24>),
          hipFuncAttributeMaxDynamicSharedMemorySize, 64 * W * 4);
    }
  }

  zero_acc<<<1, 256, 0, stream>>>();
  if (use80) {
    constexpr int NSTRIP = (H + 39) / 40;          // 13
    mega<80, 40><<<128 * NSTRIP, 1024, 80 * W * 4, stream>>>(pred, target);
  } else {
    constexpr int NSTRIP = (H + 23) / 24;          // 22
    mega<64, 24><<<128 * NSTRIP, 1024, 64 * W * 4, stream>>>(pred, target);
  }
  final_kernel<<<1, 64, 0, stream>>>(out);
}

// Round 7
// 391.395 us; speedup vs baseline: 1.7084x; 1.5447x over previous
//
#include <hip/hip_runtime.h>

// 0.8*dice_loss(pred,target) + 0.2*soft_cldice_loss(pred,target)
// pred/target: (64,1,512,512) fp32 -> 1 fp32 scalar.
//
// soft_skeletonize = 10x: x = relu(x - (dil3(ero3(x)) - ero3(x)))
//   (inner relu dropped: dil3 includes self => dil3(e) >= e; verified R10+)
//   ero3 = 3x3 min-pool, x OOB -> +inf; dil3 = 3x3 max-pool, e OOB -> -inf
//
// R15: K-STAGE REGISTER CASCADE, 3 passes (4+4+2 iterations).
// The LDS temporal-blocking family (R11/R12/R14: 547/577/526us) never beat
// the 433us streaming baseline: 1-block/CU serialization + 20 barriers +
// 2x halo redundancy + shuffle latency ate the traffic savings. Reverting
// to the PROVEN streaming structure and cutting traffic the other way:
// deepen the per-pass register pipeline from 2 to K fused iterations.
// Each stage holds 5 F8 rows (~40 VGPR): xc,xp,xn (x window), eM,eC.
// Stage i consumes stage i-1's emitted row (stage 0 reads global), emits
// y_i. Priming fills stages in order (stage j eats 5 rows from upstream).
// K=4: ~200 VGPR -> fits 256-cap at 2 waves/SIMD, no spill; ~800cy compute
// per input row covers HBM latency at 8 waves/CU (the R9/R10 prefetch
// attempts failed for lack of exactly this compute). Traffic: 1.44 GB ->
// ~1.03 GB (read-amp (5K+SROWS)/SROWS = 52/32 on K=4 passes).
//   passA: input -> g_A (iters 0-3) + dice sums on raw rows
//   passB: g_A -> g_B  (iters 4-7)
//   passC: g_B -> pairing reduction (iters 8-9, K=2, proven R8 shape)
//
// Harness rules learned: d_ws too small -> state in __device__ BSS;
// never pass __device__ symbols as host-side kernel args; launch_bounds
// must leave headroom for real register demand (R7/R12 spill disasters);
// global stores count toward vmcnt (R10).

#define H 512
#define W 512
#define NIMG 64
#define TOT 128
#define IMG_ELEMS (H * W)
#define SROWS 32
#define NSTRIPS (H / SROWS)          // 16 strips/unit
#define NDICE_SLOTS 64

__device__ float g_A[(size_t)TOT * IMG_ELEMS];    // 128 MiB
__device__ float g_B[(size_t)TOT * IMG_ELEMS];    // 128 MiB
__device__ float g_acc[NIMG * 4];                 // per-image pairing sums
__device__ float g_dice[NDICE_SLOTS * 16];        // spread dice accumulators

struct F8 { float4 a, b; };          // 8 consecutive columns per lane

__device__ __forceinline__ F8 f8fill(float v) {
  F8 r; r.a = make_float4(v, v, v, v); r.b = r.a; return r;
}
__device__ __forceinline__ F8 f8min(const F8& x, const F8& y) {
  F8 r;
  r.a.x = fminf(x.a.x, y.a.x); r.a.y = fminf(x.a.y, y.a.y);
  r.a.z = fminf(x.a.z, y.a.z); r.a.w = fminf(x.a.w, y.a.w);
  r.b.x = fminf(x.b.x, y.b.x); r.b.y = fminf(x.b.y, y.b.y);
  r.b.z = fminf(x.b.z, y.b.z); r.b.w = fminf(x.b.w, y.b.w);
  return r;
}
__device__ __forceinline__ F8 f8max(const F8& x, const F8& y) {
  F8 r;
  r.a.x = fmaxf(x.a.x, y.a.x); r.a.y = fmaxf(x.a.y, y.a.y);
  r.a.z = fmaxf(x.a.z, y.a.z); r.a.w = fmaxf(x.a.w, y.a.w);
  r.b.x = fmaxf(x.b.x, y.b.x); r.b.y = fmaxf(x.b.y, y.b.y);
  r.b.z = fmaxf(x.b.z, y.b.z); r.b.w = fmaxf(x.b.w, y.b.w);
  return r;
}
// horizontal 3-tap min; L/R image edges see +inf
__device__ __forceinline__ F8 ero8(const F8& v, int lane) {
  float L = __shfl_up(v.b.w, 1, 64);
  if (lane == 0) L = __builtin_inff();
  float R = __shfl_down(v.a.x, 1, 64);
  if (lane == 63) R = __builtin_inff();
  F8 e;
  e.a.x = fminf(L,     fminf(v.a.x, v.a.y));
  e.a.y = fminf(v.a.x, fminf(v.a.y, v.a.z));
  e.a.z = fminf(v.a.y, fminf(v.a.z, v.a.w));
  e.a.w = fminf(v.a.z, fminf(v.a.w, v.b.x));
  e.b.x = fminf(v.a.w, fminf(v.b.x, v.b.y));
  e.b.y = fminf(v.b.x, fminf(v.b.y, v.b.z));
  e.b.z = fminf(v.b.y, fminf(v.b.z, v.b.w));
  e.b.w = fminf(v.b.z, fminf(v.b.w, R));
  return e;
}
// horizontal 3-tap max; edges see -inf
__device__ __forceinline__ F8 dil8(const F8& v, int lane) {
  float L = __shfl_up(v.b.w, 1, 64);
  if (lane == 0) L = -__builtin_inff();
  float R = __shfl_down(v.a.x, 1, 64);
  if (lane == 63) R = -__builtin_inff();
  F8 d;
  d.a.x = fmaxf(L,     fmaxf(v.a.x, v.a.y));
  d.a.y = fmaxf(v.a.x, fmaxf(v.a.y, v.a.z));
  d.a.z = fmaxf(v.a.y, fmaxf(v.a.z, v.a.w));
  d.a.w = fmaxf(v.a.z, fmaxf(v.a.w, v.b.x));
  d.b.x = fmaxf(v.a.w, fmaxf(v.b.x, v.b.y));
  d.b.y = fmaxf(v.b.x, fmaxf(v.b.y, v.b.z));
  d.b.z = fmaxf(v.b.y, fmaxf(v.b.z, v.b.w));
  d.b.w = fmaxf(v.b.z, fmaxf(v.b.w, R));
  return d;
}
__device__ __forceinline__ F8 f8sub(const F8& x, const F8& y) {
  F8 r;
  r.a.x = x.a.x - y.a.x; r.a.y = x.a.y - y.a.y;
  r.a.z = x.a.z - y.a.z; r.a.w = x.a.w - y.a.w;
  r.b.x = x.b.x - y.b.x; r.b.y = x.b.y - y.b.y;
  r.b.z = x.b.z - y.b.z; r.b.w = x.b.w - y.b.w;
  return r;
}
__device__ __forceinline__ F8 f8relu_sub(const F8& x, const F8& y) {
  F8 r;
  r.a.x = fmaxf(x.a.x - y.a.x, 0.f); r.a.y = fmaxf(x.a.y - y.a.y, 0.f);
  r.a.z = fmaxf(x.a.z - y.a.z, 0.f); r.a.w = fmaxf(x.a.w - y.a.w, 0.f);
  r.b.x = fmaxf(x.b.x - y.b.x, 0.f); r.b.y = fmaxf(x.b.y - y.b.y, 0.f);
  r.b.z = fmaxf(x.b.z - y.b.z, 0.f); r.b.w = fmaxf(x.b.w - y.b.w, 0.f);
  return r;
}
__device__ __forceinline__ float f8dot(const F8& x, const float4& oa,
                                       const float4& ob) {
  return x.a.x * oa.x + x.a.y * oa.y + x.a.z * oa.z + x.a.w * oa.w
       + x.b.x * ob.x + x.b.y * ob.y + x.b.z * ob.z + x.b.w * ob.w;
}
__device__ __forceinline__ float f8sum(const F8& x) {
  return x.a.x + x.a.y + x.a.z + x.a.w + x.b.x + x.b.y + x.b.z + x.b.w;
}

// K fused skeletonize iterations, register cascade.
// Stage state (per stage i): xc=x[s], xp=x[s+1], xn=x[s+2], eM=e[s-1],
// eC=e[s]; one step consumes x[s+3] and emits y[s].
// MODE 0: store y (rows r0..r0+SROWS-1).
// MODE 1: store y; dice sums folded into stage-0 row loads:
//   isPred: a0 += sum(x*t), a1 += sum(x); else a2 += sum(x).
// MODE 2: no store; a0 += sum(y*other), a1 += sum(y).
template <int K, int MODE>
__device__ __forceinline__ void skelK(
    const float* __restrict__ src, float* __restrict__ dst,
    const float* __restrict__ oimg, bool isPred, int r0, int lane,
    float out3[3]) {
  const float PINF = __builtin_inff();
  float a0 = 0.f, a1 = 0.f, a2 = 0.f;

  F8 xc[K], xp[K], xn[K], eM[K], eC[K];
  int sr[K];                                   // wave-uniform emission rows

  int in_row = r0 - 2 * (K - 1) - 2;           // first input row consumed

  auto loadrow = [&](int r) -> F8 {
    F8 v;
    if (r >= 0 && r < H) {
      const float4* rp = (const float4*)(src + (size_t)r * W);
      v.a = rp[lane * 2];
      v.b = rp[lane * 2 + 1];
      if (MODE == 1 && r >= r0 && r < r0 + SROWS) {  // each owned row once
        if (isPred) {
          const float4* tp = (const float4*)(oimg + (size_t)r * W);
          float4 ta = tp[lane * 2], tb = tp[lane * 2 + 1];
          a0 += f8dot(v, ta, tb);
          a1 += f8sum(v);
        } else {
          a2 += f8sum(v);
        }
      }
    } else {
      v = f8fill(PINF);                        // image OOB rows: +inf
    }
    return v;
  };

  auto erow = [&](const F8& x0, const F8& x1, const F8& x2, int r) -> F8 {
    F8 e = ero8(f8min(f8min(x0, x1), x2), lane);
    if (r < 0 || r >= H) e = f8fill(-PINF);    // e OOB: -inf (dil pad)
    return e;
  };

  auto stepS = [&](int i, F8 in) -> F8 {       // i static under full unroll
    F8 eP = erow(xc[i], xp[i], xn[i], sr[i] + 1);
    F8 d  = dil8(f8max(f8max(eM[i], eC[i]), eP), lane);
    F8 y  = f8relu_sub(xc[i], f8sub(d, eC[i]));
    if (sr[i] < 0 || sr[i] >= H) y = f8fill(PINF);  // next stage sees +inf
    xc[i] = xp[i]; xp[i] = xn[i]; xn[i] = in;
    eM[i] = eC[i]; eC[i] = eP; sr[i]++;
    return y;
  };

  // step stages 0..m with one fresh top input; m is compile-time at every
  // call site (prime j uses m=j-1, main uses m=K-1) -> static indexing.
  auto cascade = [&](int m, F8 top) -> F8 {
    F8 v = top;
    #pragma unroll
    for (int i = 0; i < K; ++i)
      if (i <= m) v = stepS(i, v);
    return v;
  };

  // ---- prime stages 0..K-1 (stage j eats 5 rows from upstream) ----
  #pragma unroll
  for (int j = 0; j < K; ++j) {
    const int fj = r0 - 2 * (K - 1 - j);       // stage j first emission row
    F8 v[5];
    #pragma unroll
    for (int t = 0; t < 5; ++t)
      v[t] = cascade(j - 1, loadrow(in_row++));
    eM[j] = erow(v[0], v[1], v[2], fj - 1);
    eC[j] = erow(v[1], v[2], v[3], fj);
    xc[j] = v[2]; xp[j] = v[3]; xn[j] = v[4];
    sr[j] = fj;
  }

  // ---- main: SROWS full-cascade steps; last stage emits rows r0+t ----
  #pragma unroll 1
  for (int t = 0; t < SROWS; ++t) {
    float4 oa, ob;
    if (MODE == 2) {                           // issue operand load early;
      const float4* op =                       // consumed after ~K*200cy
          (const float4*)(oimg + (size_t)(r0 + t) * W);
      oa = op[lane * 2];
      ob = op[lane * 2 + 1];
    }
    F8 y = cascade(K - 1, loadrow(in_row++));
    if (MODE == 2) {
      a0 += f8dot(y, oa, ob);
      a1 += f8sum(y);
    } else {
      float4* dp = (float4*)(dst + (size_t)(r0 + t) * W);
      dp[lane * 2]     = y.a;
      dp[lane * 2 + 1] = y.b;
    }
  }

  if (MODE != 0) {
    #pragma unroll
    for (int o = 32; o; o >>= 1) {
      a0 += __shfl_down(a0, o, 64);
      a1 += __shfl_down(a1, o, 64);
      if (MODE == 1) a2 += __shfl_down(a2, o, 64);
    }
    out3[0] = a0; out3[1] = a1; out3[2] = a2;
  }
}

// Pass A: ext inputs -> g_A (iters 0-3) + dice sums.
__global__ __launch_bounds__(256, 2) void passA(
    const float* __restrict__ pred, const float* __restrict__ target) {
  const int wid  = blockIdx.x * 4 + (threadIdx.x >> 6);
  const int lane = threadIdx.x & 63;
  const int u    = wid / NSTRIPS;              // 0..127 (4 waves: same u)
  const int r0   = (wid % NSTRIPS) * SROWS;
  const bool isPred = (u < NIMG);
  const float* src = isPred ? pred + (size_t)u * IMG_ELEMS
                            : target + (size_t)(u - NIMG) * IMG_ELEMS;
  const float* o = isPred ? target + (size_t)u * IMG_ELEMS : nullptr;
  float* dst = (float*)g_A + (size_t)u * IMG_ELEMS;

  float out3[3] = {0.f, 0.f, 0.f};
  skelK<4, 1>(src, dst, o, isPred, r0, lane, out3);

  __shared__ float red[4][3];
  const int wave = threadIdx.x >> 6;
  if (lane == 0) {
    red[wave][0] = out3[0]; red[wave][1] = out3[1]; red[wave][2] = out3[2];
  }
  __syncthreads();
  if (threadIdx.x < 3) {
    float sv = red[0][threadIdx.x] + red[1][threadIdx.x] +
               red[2][threadIdx.x] + red[3][threadIdx.x];
    atomicAdd(&g_dice[(blockIdx.x & (NDICE_SLOTS - 1)) * 16 + threadIdx.x], sv);
  }
}

// Pass B: g_A -> g_B (iters 4-7).
__global__ __launch_bounds__(256, 2) void passB() {
  const int wid  = blockIdx.x * 4 + (threadIdx.x >> 6);
  const int lane = threadIdx.x & 63;
  const int u    = wid / NSTRIPS;
  const int r0   = (wid % NSTRIPS) * SROWS;
  skelK<4, 0>((const float*)g_A + (size_t)u * IMG_ELEMS,
              (float*)g_B + (size_t)u * IMG_ELEMS,
              nullptr, false, r0, lane, nullptr);
}

// Pass C: g_B -> iters 8,9 fused with pairing reduction.
__global__ __launch_bounds__(256) void passC(
    const float* __restrict__ pred, const float* __restrict__ target) {
  const int wid  = blockIdx.x * 4 + (threadIdx.x >> 6);
  const int lane = threadIdx.x & 63;
  const int u    = wid / NSTRIPS;
  const int r0   = (wid % NSTRIPS) * SROWS;
  const bool isPred = (u < NIMG);
  const int img = isPred ? u : u - NIMG;
  const int accBase = isPred ? 0 : 2;
  const float* src = (const float*)g_B + (size_t)u * IMG_ELEMS;
  const float* o = isPred ? target + (size_t)img * IMG_ELEMS
                          : pred + (size_t)img * IMG_ELEMS;

  float out3[3] = {0.f, 0.f, 0.f};
  skelK<2, 2>(src, nullptr, o, isPred, r0, lane, out3);

  __shared__ float red[4][2];
  const int wave = threadIdx.x >> 6;
  if (lane == 0) { red[wave][0] = out3[0]; red[wave][1] = out3[1]; }
  __syncthreads();
  if (threadIdx.x < 2) {
    float sv = red[0][threadIdx.x] + red[1][threadIdx.x] +
               red[2][threadIdx.x] + red[3][threadIdx.x];
    atomicAdd(&g_acc[img * 4 + accBase + threadIdx.x], sv);
  }
}

__global__ void zero_acc() {
  for (int i = threadIdx.x; i < NIMG * 4; i += 256) g_acc[i] = 0.0f;
  for (int i = threadIdx.x; i < NDICE_SLOTS * 16; i += 256) g_dice[i] = 0.0f;
}

__global__ void final_kernel(float* __restrict__ out) {
  const int lane = threadIdx.x;  // 64 threads = 64 images / 64 dice slots
  float s1 = g_acc[lane * 4 + 0], s2 = g_acc[lane * 4 + 1];
  float s3 = g_acc[lane * 4 + 2], s4 = g_acc[lane * 4 + 3];
  float iflat = (s1 + 1.0f) / (s2 + 1.0f);
  float tflat = (s3 + 1.0f) / (s4 + 1.0f);
  float prod = iflat * tflat;
  float ssum = iflat + tflat;
  float d0 = g_dice[lane * 16 + 0];
  float d1 = g_dice[lane * 16 + 1];
  float d2 = g_dice[lane * 16 + 2];
  #pragma unroll
  for (int o = 32; o; o >>= 1) {
    prod += __shfl_down(prod, o, 64);
    ssum += __shfl_down(ssum, o, 64);
    d0   += __shfl_down(d0, o, 64);
    d1   += __shfl_down(d1, o, 64);
    d2   += __shfl_down(d2, o, 64);
  }
  if (lane == 0) {
    float cldice = 1.0f - 2.0f * prod / ssum;
    float dice = 1.0f - (2.0f * d0 + 1e-6f) / (d1 + d2 + 1e-6f);
    out[0] = 0.8f * dice + 0.2f * cldice;
  }
}

extern "C" void kernel_launch(void* const* d_in, const int* in_sizes, int n_in,
                              void* d_out, int out_size, void* d_ws, size_t ws_size,
                              hipStream_t stream) {
  const float* pred   = (const float*)d_in[0];
  const float* target = (const float*)d_in[1];
  float* out = (float*)d_out;
  (void)d_ws; (void)ws_size;

  const int nblocks = TOT * NSTRIPS / 4;       // 512 blocks of 4 waves

  zero_acc<<<1, 256, 0, stream>>>();
  passA<<<nblocks, 256, 0, stream>>>(pred, target);  // iters 0-3 + dice
  passB<<<nblocks, 256, 0, stream>>>();              // iters 4-7
  passC<<<nblocks, 256, 0, stream>>>(pred, target);  // iters 8-9 + pairing
  final_kernel<<<1, 64, 0, stream>>>(out);
}